// Round 12
// baseline (117.994 us; speedup 1.0000x reference)
//
#include <hip/hip_runtime.h>
#include <math.h>

#define N_GAUSS 1536
#define WIDTH   160
#define HEIGHT  128
#define NPIX    (WIDTH * HEIGHT)   // 20480
#define FXC     146.44f
#define FYC     146.44f
#define CXC     80.0f
#define CYC     64.0f
#define EPS2D   0.3f
#define NEARP   0.01f
#define FARP    1e10f
#define REC     12                 // floats per gaussian record (3 x float4)
#define L2E     1.4426950408889634f

#define PREP_BLOCKS 384            // 4 gaussians/block, 1 wave (64 thr)/gaussian
#define PREP_TPB    256            // 4 waves/block; 384 blocks cover all 256 CUs
#define SCAN_LEN4   (N_GAUSS / 64 / 4)  // 6 float4 per lane

#define NWAVE   16                 // waves per raster block = depth chunks
#define RCHUNK  (N_GAUSS / NWAVE)  // 96 gaussians per depth chunk
#define RPIX    64                 // pixels per raster block (one lane each)

// fast 2^x: single v_exp_f32 on gfx950
__device__ __forceinline__ float fast_exp2(float x) {
    return __builtin_amdgcn_exp2f(x);
}

// record layout: [u, v, a2, b2 | c2, o2, r, g | b, 0, 0, 0]
// a2 = -0.5*A*log2e, b2 = -B*log2e, c2 = -0.5*C*log2e, o2 = log2(opac)
// so alpha = exp2(a2*dx^2 + b2*dx*dy + c2*dy^2 + o2); o2 = -inf when masked.

// Fused preprocess + stable rank-sort + scatter.
// 384 blocks x 256 (4 waves/block). Block b owns gaussians [b*4, b*4+4):
// ONE FULL WAVE per gaussian. Each block recomputes ALL 1536 depth keys into
// LDS (identical FP sequence in every block -> consistent ranks). All 64
// lanes of a gaussian's wave compute the body redundantly (bit-identical),
// each lane scans a 24-key 1/64th of the LDS keys, a 6-step in-wave
// shfl_xor butterfly sums the partial ranks, lane 0 scatters the record.
__global__ __launch_bounds__(PREP_TPB) void prep_sort_kernel(
    const float* __restrict__ means, const float* __restrict__ quats,
    const float* __restrict__ log_scales, const float* __restrict__ opac_logits,
    const float* __restrict__ sh, const float* __restrict__ c2w,
    float* __restrict__ sorted)
{
    __shared__ float4 k4_lds[N_GAUSS / 4];
    float* k_lds = (float*)k4_lds;

    // camera: c2w is (3,4) row-major. R = c2w[:,:3] with columns 1,2 negated.
    // R_w2c = R^T  =>  Rw[r][c] = c2w[c][r] * s_r, s = (1,-1,-1)
    float C[12];
#pragma unroll
    for (int k = 0; k < 12; k++) C[k] = c2w[k];
    float R00 =  C[0], R01 =  C[4], R02 =  C[8];
    float R10 = -C[1], R11 = -C[5], R12 = -C[9];
    float R20 = -C[2], R21 = -C[6], R22 = -C[10];
    float cpx = C[3], cpy = C[7], cpz = C[11];       // cam_pos = t_c2w
    float t0 = -(R00 * cpx + R01 * cpy + R02 * cpz);
    float t1 = -(R10 * cpx + R11 * cpy + R12 * cpz);
    float t2 = -(R20 * cpx + R21 * cpy + R22 * cpz);

    // all 1536 keys (identical FP sequence in every block -> consistent ranks)
    for (int j = threadIdx.x; j < N_GAUSS; j += PREP_TPB) {
        float mx = means[3 * j], my = means[3 * j + 1], mz = means[3 * j + 2];
        float tzj = R20 * mx + R21 * my + R22 * mz + t2;
        bool m = (tzj > NEARP) && (tzj < FARP);
        k_lds[j] = m ? tzj : INFINITY;
    }
    __syncthreads();

    int i    = blockIdx.x * 4 + (threadIdx.x >> 6);   // gaussian index (one wave)
    int part = threadIdx.x & 63;                      // lane within the wave

    float mx = means[3 * i], my = means[3 * i + 1], mz = means[3 * i + 2];
    float4 qv = ((const float4*)quats)[i];
    float lsx = log_scales[3 * i + 0];
    float lsy = log_scales[3 * i + 1];
    float lsz = log_scales[3 * i + 2];
    float olog = opac_logits[i];
    // sh as 12 independent float4 loads (one wait, no scalar-load chains)
    const float4* sh4 = (const float4*)(sh + i * 48);
    float4 S[12];
#pragma unroll
    for (int k = 0; k < 12; k++) S[k] = sh4[k];
    const float* shf = (const float*)S;

    float tx = R00 * mx + R01 * my + R02 * mz + t0;
    float ty = R10 * mx + R11 * my + R12 * mz + t1;
    float tz = R20 * mx + R21 * my + R22 * mz + t2;
    bool mask = (tz > NEARP) && (tz < FARP);

    // view dir + SH color
    float dx = mx - cpx, dy = my - cpy, dz = mz - cpz;
    float rn = rsqrtf(dx * dx + dy * dy + dz * dz);
    float x = dx * rn, y = dy * rn, z = dz * rn;
    float xx = x * x, yy = y * y, zz = z * z;
    float basis[16];
    basis[0]  = 0.282095f;
    basis[1]  = -0.488603f * y;
    basis[2]  = 0.488603f * z;
    basis[3]  = -0.488603f * x;
    basis[4]  = 1.092548f * x * y;
    basis[5]  = -1.092548f * y * z;
    basis[6]  = 0.315392f * (3.f * zz - 1.f);
    basis[7]  = -1.092548f * x * z;
    basis[8]  = 0.546274f * (xx - yy);
    basis[9]  = -0.590044f * y * (3.f * xx - yy);
    basis[10] = 2.890611f * x * y * z;
    basis[11] = -0.457046f * y * (5.f * zz - 1.f);
    basis[12] = 0.373176f * z * (5.f * zz - 3.f);
    basis[13] = -0.457046f * x * (5.f * zz - 1.f);
    basis[14] = 1.445306f * z * (xx - yy);
    basis[15] = -0.590044f * x * (xx - 3.f * yy);
    float cr = 0.f, cg = 0.f, cb = 0.f;
#pragma unroll
    for (int k = 0; k < 16; k++) {
        cr += basis[k] * shf[3 * k + 0];
        cg += basis[k] * shf[3 * k + 1];
        cb += basis[k] * shf[3 * k + 2];
    }
    cr = fmaxf(cr + 0.5f, 0.f);
    cg = fmaxf(cg + 0.5f, 0.f);
    cb = fmaxf(cb + 0.5f, 0.f);

    // quat -> rot, scaled columns, cov3d = M M^T
    float qw = qv.x, qx = qv.y, qy = qv.z, qz = qv.w;
    float qn = rsqrtf(qw * qw + qx * qx + qy * qy + qz * qz);
    qw *= qn; qx *= qn; qy *= qn; qz *= qn;
    float sx = expf(lsx);
    float sy = expf(lsy);
    float sz = expf(lsz);
    float M00 = (1.f - 2.f * (qy * qy + qz * qz)) * sx;
    float M01 = (2.f * (qx * qy - qz * qw)) * sy;
    float M02 = (2.f * (qx * qz + qy * qw)) * sz;
    float M10 = (2.f * (qx * qy + qz * qw)) * sx;
    float M11 = (1.f - 2.f * (qx * qx + qz * qz)) * sy;
    float M12 = (2.f * (qy * qz - qx * qw)) * sz;
    float M20 = (2.f * (qx * qz - qy * qw)) * sx;
    float M21 = (2.f * (qy * qz + qx * qw)) * sy;
    float M22 = (1.f - 2.f * (qx * qx + qy * qy)) * sz;
    float V00 = M00 * M00 + M01 * M01 + M02 * M02;
    float V01 = M00 * M10 + M01 * M11 + M02 * M12;
    float V02 = M00 * M20 + M01 * M21 + M02 * M22;
    float V11 = M10 * M10 + M11 * M11 + M12 * M12;
    float V12 = M10 * M20 + M11 * M21 + M12 * M22;
    float V22 = M20 * M20 + M21 * M21 + M22 * M22;

    // cov_cam = Rw V Rw^T
    float T00 = R00 * V00 + R01 * V01 + R02 * V02;
    float T01 = R00 * V01 + R01 * V11 + R02 * V12;
    float T02 = R00 * V02 + R01 * V12 + R02 * V22;
    float T10 = R10 * V00 + R11 * V01 + R12 * V02;
    float T11 = R10 * V01 + R11 * V11 + R12 * V12;
    float T12 = R10 * V02 + R11 * V12 + R12 * V22;
    float T20 = R20 * V00 + R21 * V01 + R22 * V02;
    float T21 = R20 * V01 + R21 * V11 + R22 * V12;
    float T22 = R20 * V02 + R21 * V12 + R22 * V22;
    float cc00 = T00 * R00 + T01 * R01 + T02 * R02;
    float cc01 = T00 * R10 + T01 * R11 + T02 * R12;
    float cc02 = T00 * R20 + T01 * R21 + T02 * R22;
    float cc11 = T10 * R10 + T11 * R11 + T12 * R12;
    float cc12 = T10 * R20 + T11 * R21 + T12 * R22;
    float cc22 = T20 * R20 + T21 * R21 + T22 * R22;

    // projection Jacobian, cov2d = J cov_cam J^T
    float rz = 1.f / tz;
    float rz2 = rz * rz;
    float j00 = FXC * rz, j02 = -FXC * tx * rz2;
    float j11 = FYC * rz, j12 = -FYC * ty * rz2;
    float c2d00 = j00 * j00 * cc00 + 2.f * j00 * j02 * cc02 + j02 * j02 * cc22;
    float c2d01 = (j00 * cc01 + j02 * cc12) * j11 + (j00 * cc02 + j02 * cc22) * j12;
    float c2d11 = j11 * j11 * cc11 + 2.f * j11 * j12 * cc12 + j12 * j12 * cc22;

    float a = c2d00 + EPS2D, c = c2d11 + EPS2D, b = c2d01;
    float idet = 1.f / (a * c - b * b);
    float Ac = c * idet, Bc = -b * idet, Cc = a * idet;
    float u = FXC * tx * rz + CXC;
    float v = FYC * ty * rz + CYC;
    float op = 1.f / (1.f + expf(-olog));
    // premultiplied exp2-domain conic + log2-domain opacity
    float a2 = -0.5f * L2E * Ac;
    float b2 = -L2E * Bc;
    float c2 = -0.5f * L2E * Cc;
    float o2 = log2f(op);
    if (!mask) {                       // alpha == exp2(-inf) == 0 exactly
        u = 0.f; v = 0.f; a2 = 0.f; b2 = 0.f; c2 = 0.f; o2 = -INFINITY;
    }

    // stable ascending partial rank over this lane's 1/64th of the keys
    float ki = k_lds[i];
    int rank = 0;
    int base4 = part * SCAN_LEN4;
#pragma unroll
    for (int jj = 0; jj < SCAN_LEN4; jj++) {
        int j4 = base4 + jj;
        float4 kk = k4_lds[j4];
        int j = 4 * j4;
        rank += (kk.x < ki) || (kk.x == ki && (j + 0) < i);
        rank += (kk.y < ki) || (kk.y == ki && (j + 1) < i);
        rank += (kk.z < ki) || (kk.z == ki && (j + 2) < i);
        rank += (kk.w < ki) || (kk.w == ki && (j + 3) < i);
    }
    // full-wave butterfly sum (all 64 lanes belong to this gaussian)
    rank += __shfl_xor(rank, 1);
    rank += __shfl_xor(rank, 2);
    rank += __shfl_xor(rank, 4);
    rank += __shfl_xor(rank, 8);
    rank += __shfl_xor(rank, 16);
    rank += __shfl_xor(rank, 32);

    if (part == 0) {
        float4* dst = (float4*)(sorted + rank * REC);
        dst[0] = make_float4(u, v, a2, b2);
        dst[1] = make_float4(c2, o2, cr, cg);
        dst[2] = make_float4(cb, 0.f, 0.f, 0.f);
    }
}

// Fused raster + combine: one block = 16 waves = the 16 depth chunks of the
// SAME 64 pixels. Wave w composites chunk w (96 gaussians, wave-uniform
// scalar reads of the sorted records), writes its (rgb,T) partial to LDS;
// after an intra-block __syncthreads (no device fences - see R5 lesson),
// threads 0..63 fold the 16 partials in depth order and write the image.
// Grid: NPIX/64 = 320 blocks x 1024 threads (~20 waves/CU).
__global__ __launch_bounds__(1024) void raster_kernel(
    const float4* __restrict__ sorted4, float* __restrict__ out)
{
    __shared__ float4 part_lds[NWAVE * RPIX];

    int wave = threadIdx.x >> 6;
    int lane = threadIdx.x & 63;
    int p = blockIdx.x * RPIX + lane;
    float px = (float)(p % WIDTH);
    float py = (float)(p / WIDTH);

    const float4* src = sorted4 + wave * (RCHUNK * 3);

    float T = 1.f, cr = 0.f, cg = 0.f, cb = 0.f;
#pragma unroll 4
    for (int j = 0; j < RCHUNK; j++) {
        float4 f0 = src[3 * j + 0];     // u v a2 b2
        float4 f1 = src[3 * j + 1];     // c2 o2 r g
        float4 f2 = src[3 * j + 2];     // b - - -
        float dx = px - f0.x;
        float dy = py - f0.y;
        float t  = f0.z * dx;
        t = fmaf(f0.w, dy, t);          // a2*dx + b2*dy
        float q  = f1.x * dy;           // c2*dy
        float pw = fmaf(t, dx, f1.y);   // quad + log2(op)
        pw = fmaf(q, dy, pw);
        float alpha = fminf(0.999f, fast_exp2(pw));
        float w = T * alpha;
        cr = fmaf(w, f1.z, cr);
        cg = fmaf(w, f1.w, cg);
        cb = fmaf(w, f2.x, cb);
        T -= w;                          // T *= (1 - alpha)
    }
    part_lds[wave * RPIX + lane] = make_float4(cr, cg, cb, T);
    __syncthreads();

    if (threadIdx.x < RPIX) {
        int pp = blockIdx.x * RPIX + threadIdx.x;
        float Tt = 1.f, r = 0.f, g = 0.f, b = 0.f;
#pragma unroll
        for (int c = 0; c < NWAVE; c++) {
            float4 q = part_lds[c * RPIX + threadIdx.x];
            r = fmaf(Tt, q.x, r);
            g = fmaf(Tt, q.y, g);
            b = fmaf(Tt, q.z, b);
            Tt *= q.w;
        }
        out[3 * pp + 0] = r;
        out[3 * pp + 1] = g;
        out[3 * pp + 2] = b;
    }
}

extern "C" void kernel_launch(void* const* d_in, const int* in_sizes, int n_in,
                              void* d_out, int out_size, void* d_ws, size_t ws_size,
                              hipStream_t stream) {
    const float* means       = (const float*)d_in[0];
    const float* quats       = (const float*)d_in[1];
    const float* log_scales  = (const float*)d_in[2];
    const float* opac_logits = (const float*)d_in[3];
    const float* sh          = (const float*)d_in[4];
    const float* c2w         = (const float*)d_in[5];

    float* ws     = (float*)d_ws;
    float* sorted = ws;                                   // N*12 floats

    prep_sort_kernel<<<PREP_BLOCKS, PREP_TPB, 0, stream>>>(
        means, quats, log_scales, opac_logits, sh, c2w, sorted);
    raster_kernel<<<NPIX / RPIX, NWAVE * 64, 0, stream>>>(
        (const float4*)sorted, (float*)d_out);
}

// Round 13
// 87.886 us; speedup vs baseline: 1.3426x; 1.3426x over previous
//
#include <hip/hip_runtime.h>
#include <math.h>

#define N_GAUSS 1536
#define WIDTH   160
#define HEIGHT  128
#define NPIX    (WIDTH * HEIGHT)   // 20480
#define FXC     146.44f
#define FYC     146.44f
#define CXC     80.0f
#define CYC     64.0f
#define EPS2D   0.3f
#define NEARP   0.01f
#define FARP    1e10f
#define REC     12                 // floats per gaussian record (3 x float4)
#define L2E     1.4426950408889634f

#define PREP_BLOCKS 384            // 4 gaussians/block, 1 wave (64 thr)/gaussian
#define PREP_TPB    256            // 4 waves/block; 384 blocks cover all 256 CUs
#define SCAN_LEN4   (N_GAUSS / 64 / 4)  // 6 float4 per lane

#define NWAVE   16                 // waves per raster block = depth chunks
#define RCHUNK  (N_GAUSS / NWAVE)  // 96 gaussians per depth chunk
#define RPIX    64                 // pixels per raster block (one lane each)

// fast 2^x: single v_exp_f32 on gfx950
__device__ __forceinline__ float fast_exp2(float x) {
    return __builtin_amdgcn_exp2f(x);
}

// record layout: [u, v, a2, b2 | c2, o2, r, g | b, 0, 0, 0]
// a2 = -0.5*A*log2e, b2 = -B*log2e, c2 = -0.5*C*log2e, o2 = log2(opac)
// so alpha = exp2(a2*dx^2 + b2*dx*dy + c2*dy^2 + o2); o2 = -inf when masked.

// Fused preprocess + stable rank-sort + scatter.
// 384 blocks x 256 (4 waves/block). Block b owns gaussians [b*4, b*4+4):
// ONE FULL WAVE per gaussian. Each block recomputes ALL 1536 depth keys into
// LDS (identical FP sequence in every block -> consistent ranks). All 64
// lanes of a gaussian's wave compute the body redundantly (bit-identical),
// each lane scans a 24-key 1/64th of the LDS keys, a 6-step in-wave
// shfl_xor butterfly sums the partial ranks, lane 0 scatters the record.
__global__ __launch_bounds__(PREP_TPB) void prep_sort_kernel(
    const float* __restrict__ means, const float* __restrict__ quats,
    const float* __restrict__ log_scales, const float* __restrict__ opac_logits,
    const float* __restrict__ sh, const float* __restrict__ c2w,
    float* __restrict__ sorted)
{
    __shared__ float4 k4_lds[N_GAUSS / 4];
    float* k_lds = (float*)k4_lds;

    // camera: c2w is (3,4) row-major. R = c2w[:,:3] with columns 1,2 negated.
    // R_w2c = R^T  =>  Rw[r][c] = c2w[c][r] * s_r, s = (1,-1,-1)
    float C[12];
#pragma unroll
    for (int k = 0; k < 12; k++) C[k] = c2w[k];
    float R00 =  C[0], R01 =  C[4], R02 =  C[8];
    float R10 = -C[1], R11 = -C[5], R12 = -C[9];
    float R20 = -C[2], R21 = -C[6], R22 = -C[10];
    float cpx = C[3], cpy = C[7], cpz = C[11];       // cam_pos = t_c2w
    float t0 = -(R00 * cpx + R01 * cpy + R02 * cpz);
    float t1 = -(R10 * cpx + R11 * cpy + R12 * cpz);
    float t2 = -(R20 * cpx + R21 * cpy + R22 * cpz);

    // all 1536 keys (identical FP sequence in every block -> consistent ranks)
    for (int j = threadIdx.x; j < N_GAUSS; j += PREP_TPB) {
        float mx = means[3 * j], my = means[3 * j + 1], mz = means[3 * j + 2];
        float tzj = R20 * mx + R21 * my + R22 * mz + t2;
        bool m = (tzj > NEARP) && (tzj < FARP);
        k_lds[j] = m ? tzj : INFINITY;
    }
    __syncthreads();

    int i    = blockIdx.x * 4 + (threadIdx.x >> 6);   // gaussian index (one wave)
    int part = threadIdx.x & 63;                      // lane within the wave

    float mx = means[3 * i], my = means[3 * i + 1], mz = means[3 * i + 2];
    float4 qv = ((const float4*)quats)[i];
    float lsx = log_scales[3 * i + 0];
    float lsy = log_scales[3 * i + 1];
    float lsz = log_scales[3 * i + 2];
    float olog = opac_logits[i];
    // sh as 12 independent float4 loads (one wait, no scalar-load chains)
    const float4* sh4 = (const float4*)(sh + i * 48);
    float4 S[12];
#pragma unroll
    for (int k = 0; k < 12; k++) S[k] = sh4[k];
    const float* shf = (const float*)S;

    float tx = R00 * mx + R01 * my + R02 * mz + t0;
    float ty = R10 * mx + R11 * my + R12 * mz + t1;
    float tz = R20 * mx + R21 * my + R22 * mz + t2;
    bool mask = (tz > NEARP) && (tz < FARP);

    // view dir + SH color
    float dx = mx - cpx, dy = my - cpy, dz = mz - cpz;
    float rn = rsqrtf(dx * dx + dy * dy + dz * dz);
    float x = dx * rn, y = dy * rn, z = dz * rn;
    float xx = x * x, yy = y * y, zz = z * z;
    float basis[16];
    basis[0]  = 0.282095f;
    basis[1]  = -0.488603f * y;
    basis[2]  = 0.488603f * z;
    basis[3]  = -0.488603f * x;
    basis[4]  = 1.092548f * x * y;
    basis[5]  = -1.092548f * y * z;
    basis[6]  = 0.315392f * (3.f * zz - 1.f);
    basis[7]  = -1.092548f * x * z;
    basis[8]  = 0.546274f * (xx - yy);
    basis[9]  = -0.590044f * y * (3.f * xx - yy);
    basis[10] = 2.890611f * x * y * z;
    basis[11] = -0.457046f * y * (5.f * zz - 1.f);
    basis[12] = 0.373176f * z * (5.f * zz - 3.f);
    basis[13] = -0.457046f * x * (5.f * zz - 1.f);
    basis[14] = 1.445306f * z * (xx - yy);
    basis[15] = -0.590044f * x * (xx - 3.f * yy);
    float cr = 0.f, cg = 0.f, cb = 0.f;
#pragma unroll
    for (int k = 0; k < 16; k++) {
        cr += basis[k] * shf[3 * k + 0];
        cg += basis[k] * shf[3 * k + 1];
        cb += basis[k] * shf[3 * k + 2];
    }
    cr = fmaxf(cr + 0.5f, 0.f);
    cg = fmaxf(cg + 0.5f, 0.f);
    cb = fmaxf(cb + 0.5f, 0.f);

    // quat -> rot, scaled columns, cov3d = M M^T
    float qw = qv.x, qx = qv.y, qy = qv.z, qz = qv.w;
    float qn = rsqrtf(qw * qw + qx * qx + qy * qy + qz * qz);
    qw *= qn; qx *= qn; qy *= qn; qz *= qn;
    float sx = expf(lsx);
    float sy = expf(lsy);
    float sz = expf(lsz);
    float M00 = (1.f - 2.f * (qy * qy + qz * qz)) * sx;
    float M01 = (2.f * (qx * qy - qz * qw)) * sy;
    float M02 = (2.f * (qx * qz + qy * qw)) * sz;
    float M10 = (2.f * (qx * qy + qz * qw)) * sx;
    float M11 = (1.f - 2.f * (qx * qx + qz * qz)) * sy;
    float M12 = (2.f * (qy * qz - qx * qw)) * sz;
    float M20 = (2.f * (qx * qz - qy * qw)) * sx;
    float M21 = (2.f * (qy * qz + qx * qw)) * sy;
    float M22 = (1.f - 2.f * (qx * qx + qy * qy)) * sz;
    float V00 = M00 * M00 + M01 * M01 + M02 * M02;
    float V01 = M00 * M10 + M01 * M11 + M02 * M12;
    float V02 = M00 * M20 + M01 * M21 + M02 * M22;
    float V11 = M10 * M10 + M11 * M11 + M12 * M12;
    float V12 = M10 * M20 + M11 * M21 + M12 * M22;
    float V22 = M20 * M20 + M21 * M21 + M22 * M22;

    // cov_cam = Rw V Rw^T
    float T00 = R00 * V00 + R01 * V01 + R02 * V02;
    float T01 = R00 * V01 + R01 * V11 + R02 * V12;
    float T02 = R00 * V02 + R01 * V12 + R02 * V22;
    float T10 = R10 * V00 + R11 * V01 + R12 * V02;
    float T11 = R10 * V01 + R11 * V11 + R12 * V12;
    float T12 = R10 * V02 + R11 * V12 + R12 * V22;
    float T20 = R20 * V00 + R21 * V01 + R22 * V02;
    float T21 = R20 * V01 + R21 * V11 + R22 * V12;
    float T22 = R20 * V02 + R21 * V12 + R22 * V22;
    float cc00 = T00 * R00 + T01 * R01 + T02 * R02;
    float cc01 = T00 * R10 + T01 * R11 + T02 * R12;
    float cc02 = T00 * R20 + T01 * R21 + T02 * R22;
    float cc11 = T10 * R10 + T11 * R11 + T12 * R12;
    float cc12 = T10 * R20 + T11 * R21 + T12 * R22;
    float cc22 = T20 * R20 + T21 * R21 + T22 * R22;

    // projection Jacobian, cov2d = J cov_cam J^T
    float rz = 1.f / tz;
    float rz2 = rz * rz;
    float j00 = FXC * rz, j02 = -FXC * tx * rz2;
    float j11 = FYC * rz, j12 = -FYC * ty * rz2;
    float c2d00 = j00 * j00 * cc00 + 2.f * j00 * j02 * cc02 + j02 * j02 * cc22;
    float c2d01 = (j00 * cc01 + j02 * cc12) * j11 + (j00 * cc02 + j02 * cc22) * j12;
    float c2d11 = j11 * j11 * cc11 + 2.f * j11 * j12 * cc12 + j12 * j12 * cc22;

    float a = c2d00 + EPS2D, c = c2d11 + EPS2D, b = c2d01;
    float idet = 1.f / (a * c - b * b);
    float Ac = c * idet, Bc = -b * idet, Cc = a * idet;
    float u = FXC * tx * rz + CXC;
    float v = FYC * ty * rz + CYC;
    float op = 1.f / (1.f + expf(-olog));
    // premultiplied exp2-domain conic + log2-domain opacity
    float a2 = -0.5f * L2E * Ac;
    float b2 = -L2E * Bc;
    float c2 = -0.5f * L2E * Cc;
    float o2 = log2f(op);
    if (!mask) {                       // alpha == exp2(-inf) == 0 exactly
        u = 0.f; v = 0.f; a2 = 0.f; b2 = 0.f; c2 = 0.f; o2 = -INFINITY;
    }

    // stable ascending partial rank over this lane's 1/64th of the keys
    float ki = k_lds[i];
    int rank = 0;
    int base4 = part * SCAN_LEN4;
#pragma unroll
    for (int jj = 0; jj < SCAN_LEN4; jj++) {
        int j4 = base4 + jj;
        float4 kk = k4_lds[j4];
        int j = 4 * j4;
        rank += (kk.x < ki) || (kk.x == ki && (j + 0) < i);
        rank += (kk.y < ki) || (kk.y == ki && (j + 1) < i);
        rank += (kk.z < ki) || (kk.z == ki && (j + 2) < i);
        rank += (kk.w < ki) || (kk.w == ki && (j + 3) < i);
    }
    // full-wave butterfly sum (all 64 lanes belong to this gaussian)
    rank += __shfl_xor(rank, 1);
    rank += __shfl_xor(rank, 2);
    rank += __shfl_xor(rank, 4);
    rank += __shfl_xor(rank, 8);
    rank += __shfl_xor(rank, 16);
    rank += __shfl_xor(rank, 32);

    if (part == 0) {
        float4* dst = (float4*)(sorted + rank * REC);
        dst[0] = make_float4(u, v, a2, b2);
        dst[1] = make_float4(c2, o2, cr, cg);
        dst[2] = make_float4(cb, 0.f, 0.f, 0.f);
    }
}

// Fused raster + combine: one block = 16 waves = the 16 depth chunks of the
// SAME 64 pixels. Wave w composites chunk w (96 gaussians), writes its
// (rgb,T) partial to LDS; intra-block __syncthreads (no device fences -
// R5 lesson); threads 0..63 fold the 16 partials in depth order and write
// the image. KEY FIX vs R12: the chunk index is forced into an SGPR with
// readfirstlane so the record reads take the wave-uniform SCALAR load path
// (R12's threadIdx-derived index was treated as divergent -> per-lane
// global loads -> 52 us).  Grid: 320 blocks x 1024 threads (~20 waves/CU).
__global__ __launch_bounds__(1024) void raster_kernel(
    const float4* __restrict__ sorted4, float* __restrict__ out)
{
    __shared__ float4 part_lds[NWAVE * RPIX];

    int wave = __builtin_amdgcn_readfirstlane(threadIdx.x >> 6);  // SGPR
    int lane = threadIdx.x & 63;
    int p = blockIdx.x * RPIX + lane;
    float px = (float)(p % WIDTH);
    float py = (float)(p / WIDTH);

    const float4* src = sorted4 + wave * (RCHUNK * 3);

    float T = 1.f, cr = 0.f, cg = 0.f, cb = 0.f;
#pragma unroll 4
    for (int j = 0; j < RCHUNK; j++) {
        float4 f0 = src[3 * j + 0];     // u v a2 b2
        float4 f1 = src[3 * j + 1];     // c2 o2 r g
        float4 f2 = src[3 * j + 2];     // b - - -
        float dx = px - f0.x;
        float dy = py - f0.y;
        float t  = f0.z * dx;
        t = fmaf(f0.w, dy, t);          // a2*dx + b2*dy
        float q  = f1.x * dy;           // c2*dy
        float pw = fmaf(t, dx, f1.y);   // quad + log2(op)
        pw = fmaf(q, dy, pw);
        float alpha = fminf(0.999f, fast_exp2(pw));
        float w = T * alpha;
        cr = fmaf(w, f1.z, cr);
        cg = fmaf(w, f1.w, cg);
        cb = fmaf(w, f2.x, cb);
        T -= w;                          // T *= (1 - alpha)
    }
    part_lds[wave * RPIX + lane] = make_float4(cr, cg, cb, T);
    __syncthreads();

    if (threadIdx.x < RPIX) {
        int pp = blockIdx.x * RPIX + threadIdx.x;
        float Tt = 1.f, r = 0.f, g = 0.f, b = 0.f;
#pragma unroll
        for (int c = 0; c < NWAVE; c++) {
            float4 q = part_lds[c * RPIX + threadIdx.x];
            r = fmaf(Tt, q.x, r);
            g = fmaf(Tt, q.y, g);
            b = fmaf(Tt, q.z, b);
            Tt *= q.w;
        }
        out[3 * pp + 0] = r;
        out[3 * pp + 1] = g;
        out[3 * pp + 2] = b;
    }
}

extern "C" void kernel_launch(void* const* d_in, const int* in_sizes, int n_in,
                              void* d_out, int out_size, void* d_ws, size_t ws_size,
                              hipStream_t stream) {
    const float* means       = (const float*)d_in[0];
    const float* quats       = (const float*)d_in[1];
    const float* log_scales  = (const float*)d_in[2];
    const float* opac_logits = (const float*)d_in[3];
    const float* sh          = (const float*)d_in[4];
    const float* c2w         = (const float*)d_in[5];

    float* ws     = (float*)d_ws;
    float* sorted = ws;                                   // N*12 floats

    prep_sort_kernel<<<PREP_BLOCKS, PREP_TPB, 0, stream>>>(
        means, quats, log_scales, opac_logits, sh, c2w, sorted);
    raster_kernel<<<NPIX / RPIX, NWAVE * 64, 0, stream>>>(
        (const float4*)sorted, (float*)d_out);
}